// Round 9
// baseline (201.241 us; speedup 1.0000x reference)
//
#include <hip/hip_runtime.h>
#include <math.h>

// [B=2, 1, D=192, H=192, W=192] fp32
#define W 192
#define H 192
#define DEPTH 192
#define BATCH 2
#define TH 8          // tile rows per block (full-W tile)
#define DC 12         // output planes per block
#define NT 768        // threads = 12 waves: wave w -> (row-pair w/3, col-group w%3)
#define HW (H * W)
#define VOL ((size_t)DEPTH * HW)
#define NPL (DC + 2)                  // planes swept: d0-1 .. d0+12
#define SROWS 10                      // stripe rows per plane (TH + y-halo)
#define SITEMS 960                    // float4 items per plane: 2 arrays * 10 rows * 48
#define BUFFLOATS 3840                // 960 * 4 floats per plane-buffer
#define GX (H / TH)                   // 24
#define GY (DEPTH / DC)               // 16
#define NBLK (GX * GY * BATCH)        // 768 blocks = exactly 3 per CU, zero tail

// Zero page for OOB DMA sources.
__device__ __align__(16) float g_zero16[16] = {0.f};

// R0-R8 falsified: conflicts, barrier drains, prefetch depth, residency shape,
// barrier convoy. Invariant: 158MB @ 2.2TB/s = 72us — byte-delivery-rate bound.
// Old pattern: 288-B row fragments at 768-B stride, x-split into 3 tiles -> ~35%
// DRAM efficiency. This kernel reads FULL-W tiles: one contiguous 7.5KB stripe
// (10 adjacent rows) per array per plane via global_load_lds. Compute math is
// the round-4-proven row-pair stencil; staging the round-6-proven DMA rotation.
__global__ __launch_bounds__(NT) void sobel_loss_part(
    const float* __restrict__ pred, const float* __restrict__ gt,
    const float* __restrict__ mask, float* __restrict__ partials)
{
    __shared__ __align__(16) float lds[2 * BUFFLOATS];   // 30720 B double buffer
    __shared__ float red[12];

    const int tid = threadIdx.x;
    const int ty = blockIdx.x;              // H tile (0..23)
    const int h0 = ty * TH;
    const int d0 = blockIdx.y * DC;
    const size_t base = (size_t)blockIdx.z * VOL;

    const int wvi  = tid >> 6;              // wave 0..11
    const int lane = tid & 63;
    const int pr   = wvi / 3;               // row pair 0..3 (wave-uniform)
    const int cg   = wvi % 3;               // col group 0..2 (wave-uniform)
    const int col  = cg * 64 + lane;        // 0..191 (= global col, full-W tile)

    // x-edge handling: clamped LDS offset * 0/1 mask (only col 0 / col 191 affected)
    const int   dl  = (col > 0) ? 1 : 0;
    const int   dr  = (col < W - 1) ? 1 : 0;
    const float lmk = (col > 0) ? 1.f : 0.f;
    const float rmk = (col < W - 1) ? 1.f : 0.f;

    // ---- staging geometry (2 DMA slots/thread, loop-invariant) ----
    // item j = tid + NT*k < 960: a=j/480, e=j%480, r=e/48 (stripe row), c=e%48 (col4)
    // LDS float offset = 4*j (linear) == a*1920 + r*192 + 4c  (identity).
    // Global: arr_a + p*HW + (h0-1+r)*W + 4c  -> rows contiguous: 7.5KB/stripe.
    int it_act[2], it_ok[2];
    size_t it_goff[2];
    const float* it_src[2];
    #pragma unroll
    for (int k = 0; k < 2; ++k) {
        int j = tid + NT * k;
        int act = (j < SITEMS);             // wave-uniform boundaries (960 = 15 waves)
        int jj = act ? j : 0;
        int a = jj / 480; int e = jj - a * 480;
        int r = e / 48;   int c = e - r * 48;
        int y = h0 - 1 + r;
        int rowok = ((unsigned)y < (unsigned)H);
        it_act[k]  = act;
        it_ok[k]   = act && rowok;
        it_goff[k] = it_ok[k] ? ((size_t)y * W + 4 * c) : 0;
        it_src[k]  = a ? gt : pred;
    }

    typedef const __attribute__((address_space(1))) void GV;
    typedef __attribute__((address_space(3))) void LV;

    auto dma_plane = [&](int i) {           // stage plane d0-1+i into buf[i&1]
        const int p = d0 - 1 + i;
        const bool pv = ((unsigned)p < (unsigned)DEPTH);
        float* bufp = lds + (i & 1) * BUFFLOATS;
        #pragma unroll
        for (int k = 0; k < 2; ++k) {
            if (it_act[k]) {
                const float* ga = (pv && it_ok[k])
                    ? (it_src[k] + base + (size_t)p * HW + it_goff[k]) : g_zero16;
                // LDS dest: wave-uniform base 16*(wvi*64 + NT*k) B + lane*16 (HW)
                __builtin_amdgcn_global_load_lds((GV*)ga,
                    (LV*)(bufp + (wvi << 8) + k * 3072), 16, 0, 0);
            }
        }
    };

    // output-mask pointer for this thread's two rows (global rows h0+2pr, +1)
    const float* MB = mask + base + (size_t)(h0 + 2 * pr) * W + col;
    float2 Mn = make_float2(0.f, 0.f), Mc;

    // rolling state: [array][row-in-pair][age]; ct post-shift: [1]=c(p), [0]=c(p-1)
    float dx[2][2][3], dy[2][2][3], sm[2][2][3], ct[2][2][2];
    #pragma unroll
    for (int a = 0; a < 2; ++a)
        #pragma unroll
        for (int o = 0; o < 2; ++o) {
            dx[a][o][0]=dx[a][o][1]=dx[a][o][2]=0.f;
            dy[a][o][0]=dy[a][o][1]=dy[a][o][2]=0.f;
            sm[a][o][0]=sm[a][o][1]=sm[a][o][2]=0.f;
            ct[a][o][0]=ct[a][o][1]=0.f;
        }
    float acc = 0.f;

    dma_plane(0);                           // prefetch plane d0-1

    for (int i = 0; i < NPL; ++i) {
        // Plane i's DMAs are the youngest VMEM; full drain is cheap at depth-1
        // (proven neutral R0/R4/R6 across sync structures).
        asm volatile("s_waitcnt vmcnt(0)" ::: "memory");
        __builtin_amdgcn_sched_barrier(0);
        __builtin_amdgcn_s_barrier();       // raw barrier: no compiler-forced drain
        __builtin_amdgcn_sched_barrier(0);

        Mc = Mn;
        if (i + 1 < NPL) dma_plane(i + 1);  // stage next plane into other buffer
        if (i >= 1 && i <= DC)              // prefetch masks for step i+1 (od=d0+i-1)
            Mn = make_float2(MB[(size_t)(d0 + i - 1) * HW],
                             MB[(size_t)(d0 + i - 1) * HW + W]);

        const float* buf = lds + (i & 1) * BUFFLOATS;

        // vertical-OOB rows and OOB planes hold zeros (DMA'd from zero page) --
        // no masks needed; x edges via clamped offset * lmk/rmk.
        float rs[2][4], rd[2][4], cc[2][2];
        #pragma unroll
        for (int a = 0; a < 2; ++a) {
            const int ab = a * 1920 + (2 * pr) * 192 + col;   // local row 2pr = global 2pr-1+h0... stencil rows
            #pragma unroll
            for (int rr = 0; rr < 4; ++rr) {
                const int o = ab + rr * 192;
                float m = buf[o];
                float l = buf[o - dl] * lmk;
                float r = buf[o + dr] * rmk;
                rs[a][rr] = l + 2.f * m + r;
                rd[a][rr] = r - l;
                if (rr == 1) cc[a][0] = m;
                if (rr == 2) cc[a][1] = m;
            }
        }

        #pragma unroll
        for (int a = 0; a < 2; ++a)
            #pragma unroll
            for (int o = 0; o < 2; ++o) {   // o = row within pair
                dx[a][o][0] = dx[a][o][1]; dx[a][o][1] = dx[a][o][2];
                dx[a][o][2] = rd[a][o] + 2.f * rd[a][o+1] + rd[a][o+2];
                sm[a][o][0] = sm[a][o][1]; sm[a][o][1] = sm[a][o][2];
                sm[a][o][2] = rs[a][o] + 2.f * rs[a][o+1] + rs[a][o+2];
                dy[a][o][0] = dy[a][o][1]; dy[a][o][1] = dy[a][o][2];
                dy[a][o][2] = rs[a][o] - rs[a][o+2];
                ct[a][o][0] = ct[a][o][1]; ct[a][o][1] = cc[a][o];
            }

        if (i >= 2) {                       // output plane od = d0+i-2; ct[..][0]=c(od)
            const float2 M = Mc;
            #pragma unroll
            for (int o = 0; o < 2; ++o) {
                float gxa = dx[0][o][0] + 2.f * dx[0][o][1] + dx[0][o][2];
                float gya = dy[0][o][0] + 2.f * dy[0][o][1] + dy[0][o][2];
                float gza = sm[0][o][0] - sm[0][o][2];
                float gxb = dx[1][o][0] + 2.f * dx[1][o][1] + dx[1][o][2];
                float gyb = dy[1][o][0] + 2.f * dy[1][o][1] + dy[1][o][2];
                float gzb = sm[1][o][0] - sm[1][o][2];
                float ga = __builtin_amdgcn_sqrtf(gxa * gxa + gya * gya + gza * gza + 1e-10f);
                float gb = __builtin_amdgcn_sqrtf(gxb * gxb + gyb * gyb + gzb * gzb + 1e-10f);
                float m  = o ? M.y : M.x;
                float dm = ct[0][o][0] - ct[1][o][0];
                float mse = dm * dm * m;
                float dg  = gb - ga;
                float mge = dg * dg * m;
                // tanh(x) = 1 - 2/(e^{2x}+1), x >= 0; saturates via inf -> rcp -> 0
                float ex = __expf(2.f * mge);
                float t  = 1.f - 2.f * __builtin_amdgcn_rcpf(ex + 1.f);
                acc += mse * (1.f + t);
            }
        }
    }

    // block reduction (12 waves)
    float v = acc;
    #pragma unroll
    for (int o = 32; o > 0; o >>= 1) v += __shfl_down(v, o, 64);
    if ((tid & 63) == 0) red[tid >> 6] = v;
    __syncthreads();
    if (tid == 0) {
        float bs = 0.f;
        #pragma unroll
        for (int iw = 0; iw < 12; ++iw) bs += red[iw];
        partials[(size_t)blockIdx.z * (GX * GY)
                 + (size_t)blockIdx.y * GX + blockIdx.x] = bs;
    }
}

__global__ __launch_bounds__(256) void reduce_final(
    const float* __restrict__ partials, int n, float* __restrict__ out)
{
    int tid = threadIdx.x;
    double s = 0.0;
    for (int i = tid; i < n; i += 256) s += (double)partials[i];
    #pragma unroll
    for (int o = 32; o > 0; o >>= 1) s += __shfl_down(s, o, 64);
    __shared__ double red[4];
    if ((tid & 63) == 0) red[tid >> 6] = s;
    __syncthreads();
    if (tid == 0) {
        double t = red[0] + red[1] + red[2] + red[3];
        const double ntot = (double)BATCH * (double)DEPTH * (double)H * (double)W;
        out[0] = (float)(t / ntot);
    }
}

extern "C" void kernel_launch(void* const* d_in, const int* in_sizes, int n_in,
                              void* d_out, int out_size, void* d_ws, size_t ws_size,
                              hipStream_t stream) {
    const float* pred = (const float*)d_in[0];
    const float* gt   = (const float*)d_in[1];
    const float* mask = (const float*)d_in[2];
    float* partials = (float*)d_ws;

    dim3 grid(GX, GY, BATCH);   // 24 x 16 x 2 = 768
    sobel_loss_part<<<grid, NT, 0, stream>>>(pred, gt, mask, partials);

    reduce_final<<<1, 256, 0, stream>>>(partials, NBLK, (float*)d_out);
}